// Round 3
// baseline (95.829 us; speedup 1.0000x reference)
//
#include <hip/hip_runtime.h>

// HopfRNNCellTheta: T=64 < UNITS=1024 -> z[:,0] stays 0 -> A unused,
// y_t = 0.5*(B@x_t). Harness output = REAL PART ONLY, float32[64][1024][1024]
// (out_size = 2^26; established round 2: adaptive-size run didn't fault where
// the hardcoded-512MB run did, and out_npz size matches real-only band).
// out[t][n][u] = ReY[t+u-1023][n] if t+u>=1023 else 0,
//   ReY[s][n] = 0.5*sum_m (B_re[n,m]*x_re[s,m] - B_im[n,m]*x_im[s,m]).
// ReY (64x1024 = 256KB) is stashed in the dead t=0-plane cells out[n*1024+t]
// (final value 0 since t<64<1023); fix_t0 rewrites that plane last.

#define NDIM 1024

// Kernel 1: stash[n*1024+t] = 0.5*(sum c1[n,:]*v1[t,:] + sgn*sum c2[n,:]*v2[t,:])
// 256 blocks x 256 thr; wave ng -> row n = 4*blk+ng, lane = t.
__global__ __launch_bounds__(256) void gemv_real(
    const float* __restrict__ v1, const float* __restrict__ v2,
    const float* __restrict__ c1, const float* __restrict__ c2,
    float sgn, float* outp) {
  __shared__ float s1[64][65];
  __shared__ float s2[64][65];
  const int tid = threadIdx.x;
  const int t = tid & 63;
  const int ng = tid >> 6;
  const int n = blockIdx.x * 4 + ng;
  const float* p1 = c1 + n * NDIM;
  const float* p2 = c2 + n * NDIM;
  float a1 = 0.f, a2 = 0.f;
  for (int m0 = 0; m0 < NDIM; m0 += 64) {
    __syncthreads();
#pragma unroll
    for (int k = 0; k < 16; ++k) {        // stage 64t x 64m chunk, coalesced
      const int s = tid + k * 256;
      const int tr = s >> 6, j = s & 63;
      s1[tr][j] = v1[tr * NDIM + m0 + j];
      s2[tr][j] = v2[tr * NDIM + m0 + j];
    }
    __syncthreads();
#pragma unroll 16
    for (int mm = 0; mm < 64; ++mm) {
      a1 = fmaf(p1[m0 + mm], s1[t][mm], a1);   // B row: wave-uniform L1 broadcast
      a2 = fmaf(p2[m0 + mm], s2[t][mm], a2);
    }
  }
  outp[(n << 10) + t] = 0.5f * fmaf(sgn, a2, a1);
}

// Kernel 2: fill t>=1 planes. Plane = 2^26 floats = 2^24 float4.
// q: u4=q&255 (u=4*u4+j), n=(q>>8)&1023, t=q>>18. Reads stash, coalesced stores.
__global__ __launch_bounds__(256) void expand_real(float* outp) {
  const int total = 1 << 24;
  const int stride = gridDim.x * blockDim.x;
  const float* __restrict__ stash = outp;
  float4* o4 = (float4*)outp;
  for (int q = (1 << 18) + blockIdx.x * blockDim.x + threadIdx.x; q < total;
       q += stride) {
    const int u4 = q & 255;
    const int n = (q >> 8) & 1023;
    const int t = q >> 18;
    const int sb = t + 4 * u4 - 1023;      // s for element j=0; s<=t<=63 always
    const int base = n << 10;
    float4 v = make_float4(0.f, 0.f, 0.f, 0.f);
    if (sb >= 0)     v.x = stash[base + sb];
    if (sb >= -1)    v.y = stash[base + sb + 1];
    if (sb >= -2)    v.z = stash[base + sb + 2];
    if (sb >= -3)    v.w = stash[base + sb + 3];
    o4[q] = v;
  }
}

// Kernel 3: rewrite t=0 plane. Block n: read own stash[n*1024] (barrier before
// any store), then write its 4KB row: zeros except u=1023 = ReY[0][n].
__global__ __launch_bounds__(64) void fix_t0(float* outp) {
  __shared__ float y0s;
  const int n = blockIdx.x;
  float* row = outp + (n << 10);
  if (threadIdx.x == 0) y0s = row[0];
  __syncthreads();
  const float y0 = y0s;
  float4* r4 = (float4*)row;
  for (int u4 = threadIdx.x; u4 < 256; u4 += 64) {
    float4 v = make_float4(0.f, 0.f, 0.f, 0.f);
    if (u4 == 255) v.w = y0;
    r4[u4] = v;
  }
}

extern "C" void kernel_launch(void* const* d_in, const int* in_sizes, int n_in,
                              void* d_out, int out_size, void* d_ws, size_t ws_size,
                              hipStream_t stream) {
  const float* x_re = (const float*)d_in[0];
  const float* x_im = (const float*)d_in[1];
  const float* B_re = (const float*)d_in[4];
  const float* B_im = (const float*)d_in[5];
  float* out = (float*)d_out;

  // Primary: real-part-only output (out_size == 2^26).
  // Fallback (out_size == 2^27): planar [re-plane, im-plane], same kernels.
  const int planes = (out_size >= (1 << 27)) ? 2 : 1;

  // re-plane: c1=B_re*x_re, c2=B_im*x_im, sgn=-1
  gemv_real<<<256, 256, 0, stream>>>(x_re, x_im, B_re, B_im, -1.f, out);
  if (planes == 2) {  // im-plane: B_re*x_im + B_im*x_re
    gemv_real<<<256, 256, 0, stream>>>(x_im, x_re, B_re, B_im, +1.f,
                                       out + (1 << 26));
  }
  for (int p = 0; p < planes; ++p)
    expand_real<<<4096, 256, 0, stream>>>(out + ((long long)p << 26));
  for (int p = 0; p < planes; ++p)
    fix_t0<<<1024, 64, 0, stream>>>(out + ((long long)p << 26));
}

// Round 4
// 87.129 us; speedup vs baseline: 1.0998x; 1.0998x over previous
//
#include <hip/hip_runtime.h>

// HopfRNNCellTheta: T=64 < UNITS=1024 -> z[:,0] stays 0 -> A unused,
// y_t = 0.5*(B@x_t). Output = REAL part only, float32[64][1024][1024].
// out[t][n][u] = ReY[t+u-1023][n] if t+u>=1023 (a ~3.2% band), else 0.
// Strategy: one fused kernel = {256 gemv blocks -> ReY into d_ws} +
// {8192 pure zero-fill blocks covering all 256 MB}. Fill waves give the CU
// TLP that hides gemv's latency; fill saturates HBM writes at ~10% occupancy
// (measured 6.7-6.9 TB/s on this chip's fillBuffer). Then band_write puts the
// 8.6 MB nonzero band on top. Fallback (tiny ws): round-3's 3-kernel path.

#define NDIM 1024

// ---------------- primary path ----------------

// blocks [0,256): ReY[s][n] -> stash[n*64+s] (d_ws). Wave ng -> n=4*blk+ng,
// lane = s(time). blocks [256, 8448): zero-fill d_out as float4.
__global__ __launch_bounds__(256) void gemv_and_fill(
    const float* __restrict__ x_re, const float* __restrict__ x_im,
    const float* __restrict__ B_re, const float* __restrict__ B_im,
    float* __restrict__ stash, float4* __restrict__ out4) {
  const int tid = threadIdx.x;
  if (blockIdx.x >= 256) {
    const int fb = blockIdx.x - 256;             // 0..8191
    const float4 z = make_float4(0.f, 0.f, 0.f, 0.f);
    int q = fb * 256 + tid;                      // 2^24 float4 total
#pragma unroll
    for (int k = 0; k < 8; ++k) {                // 8192*256*8 = 2^24 exactly
      out4[q] = z;
      q += 8192 * 256;
    }
    return;
  }
  __shared__ float s1[64][65];
  __shared__ float s2[64][65];
  const int t = tid & 63;
  const int ng = tid >> 6;
  const int n = blockIdx.x * 4 + ng;
  const float* p1 = B_re + n * NDIM;
  const float* p2 = B_im + n * NDIM;
  float a1 = 0.f, a2 = 0.f;
  for (int m0 = 0; m0 < NDIM; m0 += 64) {
    __syncthreads();
#pragma unroll
    for (int k = 0; k < 16; ++k) {               // stage 64t x 64m, coalesced
      const int s = tid + k * 256;
      const int tr = s >> 6, j = s & 63;
      s1[tr][j] = x_re[tr * NDIM + m0 + j];
      s2[tr][j] = x_im[tr * NDIM + m0 + j];
    }
    __syncthreads();
#pragma unroll 16
    for (int mm = 0; mm < 64; ++mm) {
      a1 = fmaf(p1[m0 + mm], s1[t][mm], a1);     // B row: wave-uniform
      a2 = fmaf(p2[m0 + mm], s2[t][mm], a2);
    }
  }
  stash[(n << 6) + t] = 0.5f * (a1 - a2);        // Re(0.5*B@x)
}

// Band: out[t][n][1023-t+s] = stash[n*64+s], s in [0,t]. Grid 1024 = (16 g)x(64 t).
// One wave handles one n-row tail: lanes = s -> contiguous stash read +
// contiguous (<=256B) output write.
__global__ __launch_bounds__(256) void band_write(
    const float* __restrict__ stash, float* __restrict__ out) {
  const int t = blockIdx.x & 63;
  const int g = blockIdx.x >> 6;
  const int wave = threadIdx.x >> 6;
  const int lane = threadIdx.x & 63;
  if (lane > t) return;
  float* plane = out + ((long long)t << 20);
  for (int no = wave; no < 64; no += 4) {
    const int n = (g << 6) + no;
    plane[(n << 10) + 1023 - t + lane] = stash[(n << 6) + lane];
  }
}

// ---------------- fallback path (round-3, known-passing) ----------------

__global__ __launch_bounds__(256) void gemv_real_fb(
    const float* __restrict__ v1, const float* __restrict__ v2,
    const float* __restrict__ c1, const float* __restrict__ c2,
    float* outp) {
  __shared__ float s1[64][65];
  __shared__ float s2[64][65];
  const int tid = threadIdx.x;
  const int t = tid & 63;
  const int ng = tid >> 6;
  const int n = blockIdx.x * 4 + ng;
  const float* p1 = c1 + n * NDIM;
  const float* p2 = c2 + n * NDIM;
  float a1 = 0.f, a2 = 0.f;
  for (int m0 = 0; m0 < NDIM; m0 += 64) {
    __syncthreads();
#pragma unroll
    for (int k = 0; k < 16; ++k) {
      const int s = tid + k * 256;
      const int tr = s >> 6, j = s & 63;
      s1[tr][j] = v1[tr * NDIM + m0 + j];
      s2[tr][j] = v2[tr * NDIM + m0 + j];
    }
    __syncthreads();
#pragma unroll 16
    for (int mm = 0; mm < 64; ++mm) {
      a1 = fmaf(p1[m0 + mm], s1[t][mm], a1);
      a2 = fmaf(p2[m0 + mm], s2[t][mm], a2);
    }
  }
  outp[(n << 10) + t] = 0.5f * (a1 - a2);
}

__global__ __launch_bounds__(256) void expand_real_fb(float* outp) {
  const int total = 1 << 24;
  const int stride = gridDim.x * blockDim.x;
  const float* __restrict__ stash = outp;
  float4* o4 = (float4*)outp;
  for (int q = (1 << 18) + blockIdx.x * blockDim.x + threadIdx.x; q < total;
       q += stride) {
    const int u4 = q & 255;
    const int n = (q >> 8) & 1023;
    const int t = q >> 18;
    const int sb = t + 4 * u4 - 1023;
    const int base = n << 10;
    float4 v = make_float4(0.f, 0.f, 0.f, 0.f);
    if (sb >= 0)  v.x = stash[base + sb];
    if (sb >= -1) v.y = stash[base + sb + 1];
    if (sb >= -2) v.z = stash[base + sb + 2];
    if (sb >= -3) v.w = stash[base + sb + 3];
    o4[q] = v;
  }
}

__global__ __launch_bounds__(64) void fix_t0_fb(float* outp) {
  __shared__ float y0s;
  const int n = blockIdx.x;
  float* row = outp + (n << 10);
  if (threadIdx.x == 0) y0s = row[0];
  __syncthreads();
  const float y0 = y0s;
  float4* r4 = (float4*)row;
  for (int u4 = threadIdx.x; u4 < 256; u4 += 64) {
    float4 v = make_float4(0.f, 0.f, 0.f, 0.f);
    if (u4 == 255) v.w = y0;
    r4[u4] = v;
  }
}

extern "C" void kernel_launch(void* const* d_in, const int* in_sizes, int n_in,
                              void* d_out, int out_size, void* d_ws, size_t ws_size,
                              hipStream_t stream) {
  (void)in_sizes; (void)n_in; (void)out_size;
  const float* x_re = (const float*)d_in[0];
  const float* x_im = (const float*)d_in[1];
  const float* B_re = (const float*)d_in[4];
  const float* B_im = (const float*)d_in[5];
  float* out = (float*)d_out;

  if (ws_size >= (size_t)(1024 * 64 * sizeof(float))) {
    float* stash = (float*)d_ws;
    gemv_and_fill<<<8448, 256, 0, stream>>>(x_re, x_im, B_re, B_im, stash,
                                            (float4*)out);
    band_write<<<1024, 256, 0, stream>>>(stash, out);
  } else {
    gemv_real_fb<<<256, 256, 0, stream>>>(x_re, x_im, B_re, B_im, out);
    expand_real_fb<<<4096, 256, 0, stream>>>(out);
    fix_t0_fb<<<1024, 64, 0, stream>>>(out);
  }
}

// Round 5
// 83.147 us; speedup vs baseline: 1.1525x; 1.0479x over previous
//
#include <hip/hip_runtime.h>

// HopfRNNCellTheta: T=64 < UNITS=1024 -> z[:,0] stays 0 -> A unused,
// y_t = 0.5*(B@x_t). Output = REAL part only, float32[64][1024][1024].
// out[t][n][u] = ReY[s][n] with s = t+u-1023 if s>=0, else 0.
//
// Single kernel, 1024 blocks (= exact 4-blocks/CU LDS capacity):
//  - blocks [0,256):  gemv -> ReY for 4 n-rows in LDS, then write the band
//    cells (s>=0) directly: per (t,n) a coalesced (t+1)-float store.
//  - blocks [256,1024): persistent grid-stride zero-fill of all s<0 bytes.
// Partition is byte-exact (fill writes component j iff sb+j<0; gemv writes
// iff s>=0), so no intra-kernel ordering is required and every output byte
// is written exactly once. No workspace, no second dispatch.

#define NDIM 1024

__global__ __launch_bounds__(256) void hopf_fused(
    const float* __restrict__ x_re, const float* __restrict__ x_im,
    const float* __restrict__ B_re, const float* __restrict__ B_im,
    float* __restrict__ out) {
  __shared__ float s1[64][65];
  __shared__ float s2[64][65];
  __shared__ float ys[4][64];
  const int tid = threadIdx.x;

  if (blockIdx.x >= 256) {
    // ---------- persistent zero-fill (out-of-band bytes only) ----------
    float4* out4 = (float4*)out;
    const float4 z = make_float4(0.f, 0.f, 0.f, 0.f);
    const int stride = 768 * 256;
    for (int q = (int)(blockIdx.x - 256) * 256 + tid; q < (1 << 24);
         q += stride) {
      const int t = q >> 18;
      const int u4 = q & 255;
      const int sb = t + 4 * u4 - 1023;       // s of component 0
      if (sb <= -4) {                          // fully out of band (~97%)
        out4[q] = z;
      } else if (sb < 0) {                     // boundary word: mixed bytes
        float* p = out + ((long long)q << 2);
        if (sb + 0 < 0) p[0] = 0.f;
        if (sb + 1 < 0) p[1] = 0.f;
        if (sb + 2 < 0) p[2] = 0.f;            // sb+3 >= 0 always here
      }
      // sb >= 0: whole word is band -> gemv block writes it
    }
    return;
  }

  // ---------- gemv: ReY[t][n] for n = blk*4 + wave, t = lane ----------
  const int t = tid & 63;
  const int ng = tid >> 6;
  const int n = blockIdx.x * 4 + ng;
  const float* p1 = B_re + n * NDIM;
  const float* p2 = B_im + n * NDIM;
  float a1 = 0.f, a2 = 0.f;
  for (int m0 = 0; m0 < NDIM; m0 += 64) {
    __syncthreads();
#pragma unroll
    for (int k = 0; k < 16; ++k) {             // stage 64t x 64m, coalesced
      const int s = tid + k * 256;
      const int tr = s >> 6, j = s & 63;
      s1[tr][j] = x_re[tr * NDIM + m0 + j];
      s2[tr][j] = x_im[tr * NDIM + m0 + j];
    }
    __syncthreads();
#pragma unroll 16
    for (int mm = 0; mm < 64; ++mm) {
      a1 = fmaf(p1[m0 + mm], s1[t][mm], a1);   // B row: wave-uniform
      a2 = fmaf(p2[m0 + mm], s2[t][mm], a2);
    }
  }
  ys[ng][t] = 0.5f * (a1 - a2);                // ReY[t][n]
  __syncthreads();

  // ---------- band write: wave ng owns row n ----------
  // out[tt][n][1023-tt+s] = ReY[s][n] for s in [0,tt]; lanes = s, coalesced.
  const float yv = ys[ng][t];                  // lane's s-value: ReY[lane][n]
  const long long rowoff = (long long)(n << 10);
  for (int tt = 0; tt < 64; ++tt) {
    if (t <= tt) {
      out[((long long)tt << 20) + rowoff + (1023 - tt) + t] = yv;
    }
  }
}

extern "C" void kernel_launch(void* const* d_in, const int* in_sizes, int n_in,
                              void* d_out, int out_size, void* d_ws, size_t ws_size,
                              hipStream_t stream) {
  (void)in_sizes; (void)n_in; (void)out_size; (void)d_ws; (void)ws_size;
  const float* x_re = (const float*)d_in[0];
  const float* x_im = (const float*)d_in[1];
  const float* B_re = (const float*)d_in[4];
  const float* B_im = (const float*)d_in[5];
  hopf_fused<<<1024, 256, 0, stream>>>(x_re, x_im, B_re, B_im, (float*)d_out);
}

// Round 6
// 62.646 us; speedup vs baseline: 1.5297x; 1.3272x over previous
//
#include <hip/hip_runtime.h>

// HopfRNNCellTheta: T=64 < UNITS=1024 -> z[:,0] stays 0 -> A unused,
// y_t = 0.5*(B@x_t). Output = REAL part only, float32[64][1024][1024].
// out[t][n][u] = ReY[s][n], s = t+u-1023, if s>=0 else 0.
//
// 1024 blocks = 1 gemv + 3 fill per CU (exact byte partition, single pass):
//  - blocks [0,256): gemv for 4 n-rows; B chunk in LDS (uniform float4
//    reads), x chunk transposed in LDS (conflict-free), register
//    double-buffer prefetch of the next chunk; then write band cells (s>=0).
//  - blocks [256,1024): persistent zero-fill of all s<0 words.

#define NDIM 1024

__global__ __launch_bounds__(256) void hopf_fused(
    const float* __restrict__ x_re, const float* __restrict__ x_im,
    const float* __restrict__ B_re, const float* __restrict__ B_im,
    float* __restrict__ out) {
  __shared__ float xs1[64][65];   // transposed: xs1[m][t], stride 65 (CF banks)
  __shared__ float xs2[64][65];
  __shared__ float bs1[4][68];    // 68 -> 272B rows, 16B-aligned for float4
  __shared__ float bs2[4][68];
  const int tid = threadIdx.x;

  if (blockIdx.x >= 256) {
    // ---------- persistent zero-fill (out-of-band words only) ----------
    float4* out4 = (float4*)out;
    const float4 z = make_float4(0.f, 0.f, 0.f, 0.f);
    const int stride = 768 * 256;
    for (int q = (int)(blockIdx.x - 256) * 256 + tid; q < (1 << 24);
         q += stride) {
      const int t = q >> 18;
      const int u4 = q & 255;
      const int sb = t + 4 * u4 - 1023;      // s of word component 0
      if (sb <= -4) {                         // fully out of band (~97%)
        out4[q] = z;
      } else if (sb < 0) {                    // boundary word: mixed bytes
        float* p = out + ((long long)q << 2);
        p[0] = 0.f;
        if (sb + 1 < 0) p[1] = 0.f;
        if (sb + 2 < 0) p[2] = 0.f;           // sb+3 >= 0 always here
      }
    }
    return;
  }

  // ---------- gemv: ReY[t][n], wave ng -> n = blk*4+ng, lane = t ----------
  __builtin_amdgcn_s_setprio(1);
  const int t = tid & 63;
  const int ng = tid >> 6;
  const int n = blockIdx.x * 4 + ng;
  const int tr = (tid >> 4);                  // x-load row within k-group
  const int j0 = (tid & 15) * 4;              // x-load col (float4)

  float4 r1[4], r2[4];
  float bb1, bb2;
  float a1 = 0.f, a2 = 0.f;

  // prefetch chunk 0
#pragma unroll
  for (int k = 0; k < 4; ++k) {
    r1[k] = *(const float4*)(x_re + (k * 16 + tr) * NDIM + j0);
    r2[k] = *(const float4*)(x_im + (k * 16 + tr) * NDIM + j0);
  }
  bb1 = B_re[n * NDIM + t];
  bb2 = B_im[n * NDIM + t];

  for (int c = 0; c < 16; ++c) {
    // store prefetched chunk to LDS (transposed x; conflict-free)
#pragma unroll
    for (int k = 0; k < 4; ++k) {
      const int row = k * 16 + tr;
      xs1[j0 + 0][row] = r1[k].x;
      xs1[j0 + 1][row] = r1[k].y;
      xs1[j0 + 2][row] = r1[k].z;
      xs1[j0 + 3][row] = r1[k].w;
      xs2[j0 + 0][row] = r2[k].x;
      xs2[j0 + 1][row] = r2[k].y;
      xs2[j0 + 2][row] = r2[k].z;
      xs2[j0 + 3][row] = r2[k].w;
    }
    bs1[ng][t] = bb1;
    bs2[ng][t] = bb2;
    __syncthreads();

    // issue next chunk's global loads (latency hides under compute)
    if (c < 15) {
      const int m0 = (c + 1) * 64;
#pragma unroll
      for (int k = 0; k < 4; ++k) {
        r1[k] = *(const float4*)(x_re + (k * 16 + tr) * NDIM + m0 + j0);
        r2[k] = *(const float4*)(x_im + (k * 16 + tr) * NDIM + m0 + j0);
      }
      bb1 = B_re[n * NDIM + m0 + t];
      bb2 = B_im[n * NDIM + m0 + t];
    }

    // compute: B via wave-uniform float4 LDS reads, x via CF b32 reads
#pragma unroll
    for (int m4 = 0; m4 < 16; ++m4) {
      const float4 b1 = *(const float4*)&bs1[ng][m4 * 4];
      const float4 b2 = *(const float4*)&bs2[ng][m4 * 4];
      const int mm = m4 * 4;
      a1 = fmaf(b1.x, xs1[mm + 0][t], a1);
      a2 = fmaf(b2.x, xs2[mm + 0][t], a2);
      a1 = fmaf(b1.y, xs1[mm + 1][t], a1);
      a2 = fmaf(b2.y, xs2[mm + 1][t], a2);
      a1 = fmaf(b1.z, xs1[mm + 2][t], a1);
      a2 = fmaf(b2.z, xs2[mm + 2][t], a2);
      a1 = fmaf(b1.w, xs1[mm + 3][t], a1);
      a2 = fmaf(b2.w, xs2[mm + 3][t], a2);
    }
    __syncthreads();
  }

  // ---------- band write: lane t holds ReY[t][n] ----------
  const float yv = 0.5f * (a1 - a2);
  const long long rowoff = (long long)(n << 10);
  for (int tt = 0; tt < 64; ++tt) {
    if (t <= tt) {
      out[((long long)tt << 20) + rowoff + (1023 - tt) + t] = yv;
    }
  }
}

extern "C" void kernel_launch(void* const* d_in, const int* in_sizes, int n_in,
                              void* d_out, int out_size, void* d_ws, size_t ws_size,
                              hipStream_t stream) {
  (void)in_sizes; (void)n_in; (void)out_size; (void)d_ws; (void)ws_size;
  const float* x_re = (const float*)d_in[0];
  const float* x_im = (const float*)d_in[1];
  const float* B_re = (const float*)d_in[4];
  const float* B_im = (const float*)d_in[5];
  hopf_fused<<<1024, 256, 0, stream>>>(x_re, x_im, B_re, B_im, (float*)d_out);
}